// Round 3
// baseline (904.509 us; speedup 1.0000x reference)
//
#include <hip/hip_runtime.h>

// SIRD RK4 batch integrator, round 3: depth-8 recurrence.
// Carry u = c*S - gm as a state variable so stage-u values derive directly
// from P = S*I products (u_k = u - c^2*h*P_{k-1}), removing the S->u detour.
// Loop-carried critical path: 8 dependent ops/substep (was 11).
//
//   dI = I*u,  dS = -c*P,  dD = mu*I,  with u = c*S - gm, P = S*I.
// Final combines: X_new = fma(coef, last_term, base) with base ready early.

#define N_POP 1.0e7f
#define SUBSTEPS 8
#define T_PTS 2048

__global__ __launch_bounds__(64, 1) void sird_kernel(const float* __restrict__ alpha,
                                                     float* __restrict__ out) {
    const int s = blockIdx.x * blockDim.x + threadIdx.x;

    const float beta  = alpha[s * 3 + 0];
    const float gamma = alpha[s * 3 + 1];
    const float mu    = alpha[s * 3 + 2];

    const float c    = beta * (1.0f / N_POP);  // beta/N
    const float gm   = gamma + mu;
    const float dt   = 1.0f / SUBSTEPS;
    const float hdt  = 0.5f * dt;
    const float w    = dt / 6.0f;
    const float nhc  = -(hdt * c);             // -hdt*c      (S stage upd)
    const float ndc  = -(dt * c);              // -dt*c
    const float nwc  = -(w * c);               // -w*c        (S combine)
    const float nhcc = nhc * c;                // -hdt*c^2    (u stage upd)
    const float ndcc = ndc * c;                // -dt*c^2
    const float nwcc = nwc * c;                // -w*c^2      (u combine)
    const float wmu  = w * mu;

    float S = N_POP - 1.0f;
    float I = 1.0f;
    float u = __builtin_fmaf(c, S, -gm);
    float D = 0.0f;

    float2* __restrict__ orow = (float2*)out + (size_t)s * T_PTS;
    orow[0] = make_float2(1.0f, 0.0f);

    for (int tstep = 1; tstep < T_PTS; ++tstep) {
#pragma unroll
        for (int sub = 0; sub < SUBSTEPS; ++sub) {
            // depth annotations: d(X) = dependent-op depth from substep entry
            const float P1  = S * I;                          // 1
            const float kI1 = I * u;                          // 1
            const float I2  = __builtin_fmaf(hdt, kI1, I);    // 2
            const float u2  = __builtin_fmaf(nhcc, P1, u);    // 2
            const float S2  = __builtin_fmaf(nhc,  P1, S);    // 2
            const float kI2 = I2 * u2;                        // 3
            const float P2  = S2 * I2;                        // 3
            const float I3  = __builtin_fmaf(hdt, kI2, I);    // 4
            const float u3  = __builtin_fmaf(nhcc, P2, u);    // 4
            const float S3  = __builtin_fmaf(nhc,  P2, S);    // 4
            const float kI3 = I3 * u3;                        // 5
            const float P3  = S3 * I3;                        // 5
            const float I4  = __builtin_fmaf(dt, kI3, I);     // 6
            const float u4  = __builtin_fmaf(ndcc, P3, u);    // 6
            const float S4  = __builtin_fmaf(ndc,  P3, S);    // 6
            const float kI4 = I4 * u4;                        // 7
            const float P4  = S4 * I4;                        // 7
            // combine trees (slack; ready by depth 7)
            const float tI1 = __builtin_fmaf(2.0f, kI2, kI1); // 4
            const float tI2 = __builtin_fmaf(2.0f, kI3, tI1); // 6
            const float tP1 = __builtin_fmaf(2.0f, P2, P1);   // 4
            const float tP2 = __builtin_fmaf(2.0f, P3, tP1);  // 6
            const float sD1 = __builtin_fmaf(2.0f, I2, I);    // 3
            const float sD2 = __builtin_fmaf(2.0f, I3, sD1);  // 5
            const float sD  = sD2 + I4;                       // 7
            const float bI  = __builtin_fmaf(w,    tI2, I);   // 7
            const float bS  = __builtin_fmaf(nwc,  tP2, S);   // 7
            const float bU  = __builtin_fmaf(nwcc, tP2, u);   // 7
            I = __builtin_fmaf(w,    kI4, bI);                // 8
            S = __builtin_fmaf(nwc,  P4,  bS);                // 8
            u = __builtin_fmaf(nwcc, P4,  bU);                // 8
            D = __builtin_fmaf(wmu,  sD,  D);                 // 8 (slack chain)
        }
        orow[tstep] = make_float2(I, D);
    }
}

extern "C" void kernel_launch(void* const* d_in, const int* in_sizes, int n_in,
                              void* d_out, int out_size, void* d_ws, size_t ws_size,
                              hipStream_t stream) {
    const float* alpha = (const float*)d_in[0];
    float* out = (float*)d_out;
    sird_kernel<<<dim3(T_PTS / 64), dim3(64), 0, stream>>>(alpha, out);
}

// Round 4
// 714.739 us; speedup vs baseline: 1.2655x; 1.2655x over previous
//
#include <hip/hip_runtime.h>

// SIRD RK4, round 4: instruction-count-minimized (single-wave issue cadence
// ~4 cyc/inst is the measured binding constraint, NOT dep-chain depth).
//
// (a) D is never integrated: RK4 preserves S+I+R+D=N exactly (linear
//     invariant) and D=(mu/gm)*(R+D) exactly (D,R are the same weighted
//     stage-sum of I scaled by mu vs gamma) => D = (mu/gm)*(N-S-I).
// (b) Packed fp32 (v_pk_fma_f32): state packs X=(S,I), Y=(u,I) with
//     u = c*S-gm; stage products PK=(P,kI)=X*Y.yx feed both packs
//     element-aligned, so only the muls need an op_sel swizzle.
// 15 packed VALU insts/substep vs ~31 scalar in round 3.

typedef float v2f __attribute__((ext_vector_type(2)));

#define N_POP 1.0e7f
#define SUBSTEPS 8
#define T_PTS 2048

__global__ __launch_bounds__(64, 1) void sird_kernel(const float* __restrict__ alpha,
                                                     float* __restrict__ out) {
    const int s = blockIdx.x * blockDim.x + threadIdx.x;

    const float beta  = alpha[s * 3 + 0];
    const float gamma = alpha[s * 3 + 1];
    const float mu    = alpha[s * 3 + 2];

    const float c    = beta * (1.0f / N_POP);
    const float gm   = gamma + mu;
    const float dt   = 1.0f / SUBSTEPS;
    const float hdt  = 0.5f * dt;
    const float w    = dt / 6.0f;
    const float nhc  = -(hdt * c);   // -h/2 * c   (S stage)
    const float ndc  = -(dt * c);    // -h   * c
    const float nwc  = -(w * c);     // -w   * c   (S combine)
    const float nhcc = nhc * c;      // u stage coefs (u = c*S - gm)
    const float ndcc = ndc * c;
    const float nwcc = nwc * c;
    const float kD   = (gm > 0.0f) ? (mu / gm) : 0.0f;
    const float kDN  = kD * (float)N_POP;

    // packed coefficients; PK ordering is (P, kI)
    const v2f CH_X = {nhc,  hdt};   // (S,I) half-step
    const v2f CD_X = {ndc,  dt};    // (S,I) full-step
    const v2f CW_X = {nwc,  w};     // (S,I) combine
    const v2f CH_Y = {nhcc, hdt};   // (u,I) half-step
    const v2f CD_Y = {ndcc, dt};    // (u,I) full-step
    const v2f CW_Y = {nwcc, w};     // (u,I) combine
    const v2f TWO  = {2.0f, 2.0f};

    const float S0 = N_POP - 1.0f;
    v2f X = {S0, 1.0f};                              // (S, I)
    v2f Y = {__builtin_fmaf(c, S0, -gm), 1.0f};      // (u, I) — both halves track I identically

    float2* __restrict__ orow = (float2*)out + (size_t)s * T_PTS;
    orow[0] = make_float2(1.0f, 0.0f);

    for (int tstep = 1; tstep < T_PTS; ++tstep) {
#pragma unroll
        for (int sub = 0; sub < SUBSTEPS; ++sub) {
            const v2f PK1 = X * Y.yx;                                 // (P1,kI1) = (S*I, I*u)
            const v2f X2  = __builtin_elementwise_fma(CH_X, PK1, X);  // (S2,I2)
            const v2f Y2  = __builtin_elementwise_fma(CH_Y, PK1, Y);  // (u2,I2)
            const v2f PK2 = X2 * Y2.yx;
            const v2f X3  = __builtin_elementwise_fma(CH_X, PK2, X);
            const v2f Y3  = __builtin_elementwise_fma(CH_Y, PK2, Y);
            const v2f PK3 = X3 * Y3.yx;
            const v2f X4  = __builtin_elementwise_fma(CD_X, PK3, X);
            const v2f Y4  = __builtin_elementwise_fma(CD_Y, PK3, Y);
            const v2f PK4 = X4 * Y4.yx;
            const v2f Ta  = PK1 + PK4;                                // weights 1,2,2,1
            const v2f Tb  = PK2 + PK3;
            const v2f T   = __builtin_elementwise_fma(TWO, Tb, Ta);   // (ΣP, ΣkI)
            X = __builtin_elementwise_fma(CW_X, T, X);
            Y = __builtin_elementwise_fma(CW_Y, T, Y);
        }
        const float Dv = __builtin_fmaf(-kD, X.x + X.y, kDN);         // D = kD*(N-S-I)
        orow[tstep] = make_float2(X.y, Dv);
    }
}

extern "C" void kernel_launch(void* const* d_in, const int* in_sizes, int n_in,
                              void* d_out, int out_size, void* d_ws, size_t ws_size,
                              hipStream_t stream) {
    const float* alpha = (const float*)d_in[0];
    float* out = (float*)d_out;
    sird_kernel<<<dim3(T_PTS / 64), dim3(64), 0, stream>>>(alpha, out);
}